// Round 2
// baseline (1450.351 us; speedup 1.0000x reference)
//
#include <hip/hip_runtime.h>
#include <hip/hip_fp16.h>
#include <hip/hip_cooperative_groups.h>

namespace cg = cooperative_groups;

#define NN 262144
#define NCC 4096
#define DD 5
#define KK 4
#define PRE_IT 3
#define POST_IT 3
#define COARSE_IT 10
#define WJ ((float)(2.0/3.0))

__device__ __forceinline__ unsigned pack_ch(unsigned col, float v) {
  return col | ((unsigned)__half_as_ushort(__float2half(v)) << 16);
}
__device__ __forceinline__ float unpack_h(unsigned w) {
  return __half2float(__ushort_as_half((unsigned short)(w >> 16)));
}

// ---------------- histogram of P_cols over NC buckets + pack P rows to 16B ----------------
__global__ __launch_bounds__(1024) void k_hist(const int4* __restrict__ pc4,
                                               const float4* __restrict__ pv4,
                                               unsigned* __restrict__ cnt,
                                               uint4* __restrict__ Ppack) {
  __shared__ unsigned h[NCC];
  const int tid = threadIdx.x;
  for (int q = tid; q < NCC; q += 1024) h[q] = 0u;
  __syncthreads();
  const int base = blockIdx.x * 4096;
#pragma unroll
  for (int rr = 0; rr < 4; ++rr) {
    const int r = base + rr * 1024 + tid;
    int4 pc = pc4[r];
    float4 pv = pv4[r];
    Ppack[r] = make_uint4(pack_ch((unsigned)pc.x, pv.x), pack_ch((unsigned)pc.y, pv.y),
                          pack_ch((unsigned)pc.z, pv.z), pack_ch((unsigned)pc.w, pv.w));
    atomicAdd(&h[pc.x], 1u); atomicAdd(&h[pc.y], 1u);
    atomicAdd(&h[pc.z], 1u); atomicAdd(&h[pc.w], 1u);
  }
  __syncthreads();
  for (int q = tid; q < NCC; q += 1024) { unsigned v = h[q]; if (v) atomicAdd(&cnt[q], v); }
}

// ---------------- exclusive scan of 4096 counts (single block) ----------------
__global__ __launch_bounds__(1024) void k_scan(unsigned* __restrict__ cnt_cursor,
                                               unsigned* __restrict__ offs) {
  __shared__ unsigned sv[1024];
  const int t = threadIdx.x;
  unsigned c0 = cnt_cursor[t*4+0], c1 = cnt_cursor[t*4+1],
           c2 = cnt_cursor[t*4+2], c3 = cnt_cursor[t*4+3];
  unsigned s = c0 + c1 + c2 + c3;
  sv[t] = s; __syncthreads();
  for (int off = 1; off < 1024; off <<= 1) {
    unsigned v = (t >= off) ? sv[t-off] : 0u;
    __syncthreads();
    sv[t] += v;
    __syncthreads();
  }
  unsigned run = sv[t] - s;
  unsigned o0 = run, o1 = run + c0, o2 = o1 + c1, o3 = o2 + c2;
  offs[t*4+0] = o0; offs[t*4+1] = o1; offs[t*4+2] = o2; offs[t*4+3] = o3;
  cnt_cursor[t*4+0] = o0; cnt_cursor[t*4+1] = o1;
  cnt_cursor[t*4+2] = o2; cnt_cursor[t*4+3] = o3;
  if (t == 1023) offs[4096] = sv[1023];
}

// ---------------- ranked scatter of {fine row, pv} into coarse-row buckets ----------------
__global__ __launch_bounds__(1024) void k_scatter(const int4* __restrict__ pc4,
                                                  const float4* __restrict__ pv4,
                                                  unsigned* __restrict__ cursor,
                                                  uint2* __restrict__ pairs8) {
  __shared__ unsigned h[NCC];
  __shared__ unsigned basec[NCC];
  const int tid = threadIdx.x;
  for (int q = tid; q < NCC; q += 1024) h[q] = 0u;
  __syncthreads();
  const int rbase = blockIdx.x * 4096;
  int4 pc[4]; float4 pv[4];
#pragma unroll
  for (int rr = 0; rr < 4; ++rr) {
    pc[rr] = pc4[rbase + rr * 1024 + tid];
    pv[rr] = pv4[rbase + rr * 1024 + tid];
    atomicAdd(&h[pc[rr].x], 1u); atomicAdd(&h[pc[rr].y], 1u);
    atomicAdd(&h[pc[rr].z], 1u); atomicAdd(&h[pc[rr].w], 1u);
  }
  __syncthreads();
  for (int q = tid; q < NCC; q += 1024) {
    unsigned v = h[q];
    basec[q] = v ? atomicAdd(&cursor[q], v) : 0u;
  }
  __syncthreads();
  for (int q = tid; q < NCC; q += 1024) h[q] = 0u;
  __syncthreads();
#pragma unroll
  for (int rr = 0; rr < 4; ++rr) {
    const unsigned g = (unsigned)(rbase + rr * 1024 + tid);
    unsigned r;
    r = atomicAdd(&h[pc[rr].x], 1u); pairs8[basec[pc[rr].x] + r] = make_uint2(g, __float_as_uint(pv[rr].x));
    r = atomicAdd(&h[pc[rr].y], 1u); pairs8[basec[pc[rr].y] + r] = make_uint2(g, __float_as_uint(pv[rr].y));
    r = atomicAdd(&h[pc[rr].z], 1u); pairs8[basec[pc[rr].z] + r] = make_uint2(g, __float_as_uint(pv[rr].z));
    r = atomicAdd(&h[pc[rr].w], 1u); pairs8[basec[pc[rr].w] + r] = make_uint2(g, __float_as_uint(pv[rr].w));
  }
}

// ---------------- Y = A*P row-wise: 20 packed (u16 col, half val) per fine row (80B) ----------------
__global__ __launch_bounds__(1024) void k_buildY(const float* __restrict__ A_vals,
                                                 const int* __restrict__ A_cols,
                                                 const uint4* __restrict__ Ppack,
                                                 unsigned* __restrict__ Y) {
  const unsigned g = blockIdx.x * 1024u + threadIdx.x;
  int ac[DD]; float av[DD];
#pragma unroll
  for (int j = 0; j < DD; ++j) { ac[j] = A_cols[g*DD+j]; av[j] = A_vals[g*DD+j]; }
  uint4 pr[DD];
#pragma unroll
  for (int j = 0; j < DD; ++j) pr[j] = Ppack[ac[j]];   // 5 independent random 16B gathers (4MB array)
  uint4* yp = (uint4*)(Y + 20u * g);                   // 80B, 16B-aligned
#pragma unroll
  for (int j = 0; j < DD; ++j) {
    uint4 o;
    o.x = pack_ch(pr[j].x & 0xffffu, av[j] * unpack_h(pr[j].x));
    o.y = pack_ch(pr[j].y & 0xffffu, av[j] * unpack_h(pr[j].y));
    o.z = pack_ch(pr[j].z & 0xffffu, av[j] * unpack_h(pr[j].z));
    o.w = pack_ch(pr[j].w & 0xffffu, av[j] * unpack_h(pr[j].w));
    yp[j] = o;
  }
}

// ---------------- the whole V-cycle: one cooperative kernel ----------------
__global__ __launch_bounds__(1024, 4) void k_mega(
    const float* __restrict__ b, const float* __restrict__ x_in,
    const float* __restrict__ A_vals, const float* __restrict__ P_vals,
    const int* __restrict__ A_cols, const int* __restrict__ P_cols,
    const int* __restrict__ num_p,
    const unsigned* __restrict__ offs, const uint2* __restrict__ pairs8,
    const unsigned* __restrict__ Y,
    float* __restrict__ partials, float* __restrict__ x2,
    float* __restrict__ xcA, float* __restrict__ xcB,
    float* __restrict__ out) {
  extern __shared__ char smem[];
  __half* slab  = (__half*)smem;                           // 131072 B
  float* rowbuf = (float*)(smem + 131072);                 // 16384 B
  float* wdiag  = (float*)(smem + 131072 + 16384);         // 64 B
  float* bcl    = (float*)(smem + 131072 + 16384 + 64);    // 64 B

  cg::grid_group grid = cg::this_grid();
  const int tid = threadIdx.x;
  const int blk = blockIdx.x;
  const int g = (blk << 10) + tid;

  // ---- build phase: one thread per pair; per pair 8B seq + 80B (2 lines) random ----
  for (int rr = 0; rr < 16; ++rr) {
    const int c1 = (blk << 4) + rr;
    for (int q = tid; q < NCC; q += 1024) rowbuf[q] = 0.f;
    __syncthreads();
    const unsigned p0 = offs[c1], p1 = offs[c1 + 1];
    for (unsigned p = p0 + tid; p < p1; p += 1024) {
      const uint2 e = pairs8[p];
      const float pv = __uint_as_float(e.y);
      const uint4* yp = (const uint4*)(Y + 20u * e.x);
      uint4 v0 = yp[0], v1 = yp[1], v2 = yp[2], v3 = yp[3], v4 = yp[4];
#define SCAT(v) \
      atomicAdd(&rowbuf[v.x & 0xffffu], pv * unpack_h(v.x)); \
      atomicAdd(&rowbuf[v.y & 0xffffu], pv * unpack_h(v.y)); \
      atomicAdd(&rowbuf[v.z & 0xffffu], pv * unpack_h(v.z)); \
      atomicAdd(&rowbuf[v.w & 0xffffu], pv * unpack_h(v.w));
      SCAT(v0); SCAT(v1); SCAT(v2); SCAT(v3); SCAT(v4);
#undef SCAT
    }
    __syncthreads();
    if (tid == 0) wdiag[rr] = WJ / rowbuf[c1];
    for (int q = tid; q < NCC; q += 1024) slab[(rr << 12) + q] = __float2half(rowbuf[q]);
    __syncthreads();
  }
  grid.sync();   // Y is dead after this; partials/x2 alias its storage

  const int num = num_p[0];
  if (num <= 0) { out[g] = x_in[g]; return; }

  float av[DD]; int ac[DD];
#pragma unroll
  for (int j = 0; j < DD; ++j) { av[j] = A_vals[g * DD + j]; ac[j] = A_cols[g * DD + j]; }
  const float bg = b[g];
  const float wdg = WJ / av[0];
  const int4 pcg = ((const int4*)P_cols)[g];
  const float4 pvg = ((const float4*)P_vals)[g];

  const float* xr = x_in;
  int wi = 0;

  for (int cyc = 0; cyc < num; ++cyc) {
    // ---- pre-smooth x3 ----
    for (int it = 0; it < PRE_IT; ++it) {
      float s = 0.f;
#pragma unroll
      for (int j = 0; j < DD; ++j) s += av[j] * xr[ac[j]];
      const float xn = xr[g] + (bg - s) * wdg;
      float* wb = (wi == 0) ? x2 : out;
      wb[g] = xn;
      xr = wb; wi ^= 1;
      grid.sync();
    }
    // ---- residual + block-partial restriction ----
    {
      float s = 0.f;
#pragma unroll
      for (int j = 0; j < DD; ++j) s += av[j] * xr[ac[j]];
      const float r = bg - s;
      for (int q = tid; q < NCC; q += 1024) rowbuf[q] = 0.f;
      __syncthreads();
      atomicAdd(&rowbuf[pcg.x], pvg.x * r);
      atomicAdd(&rowbuf[pcg.y], pvg.y * r);
      atomicAdd(&rowbuf[pcg.z], pvg.z * r);
      atomicAdd(&rowbuf[pcg.w], pvg.w * r);
      __syncthreads();
      for (int q = tid; q < NCC; q += 1024) partials[(blk << 12) + q] = rowbuf[q];
      grid.sync();
    }
    // ---- reduce partials -> bc + coarse iteration 0 ----
    {
      for (int q = tid; q < 4096; q += 1024) {
        const int t2 = q >> 4, c = q & 15;
        rowbuf[q] = partials[(t2 << 12) + (blk << 4) + c];
      }
      __syncthreads();
      if (tid < 16) {
        float sum = 0.f;
#pragma unroll 8
        for (int t2 = 0; t2 < 256; ++t2) sum += rowbuf[(t2 << 4) + tid];
        bcl[tid] = sum;
        xcA[(blk << 4) + tid] = sum * wdiag[tid];
      }
      grid.sync();
    }
    // ---- coarse Jacobi iterations 1..9 (LDS-resident fp16 Ac) ----
    const float* xc_cur = xcA;
    float* xc_nxt = xcB;
    for (int it = 1; it < COARSE_IT; ++it) {
      const int w = tid >> 6, l = tid & 63;
      const float4 xv = ((const float4*)xc_cur)[(w << 6) + l];
      float acc[16];
#pragma unroll
      for (int r2 = 0; r2 < 16; ++r2) {
        const __half2* hp2 = (const __half2*)(slab + (r2 << 12) + (w << 8) + (l << 2));
        const float2 f01 = __half22float2(hp2[0]);
        const float2 f23 = __half22float2(hp2[1]);
        acc[r2] = f01.x * xv.x + f01.y * xv.y + f23.x * xv.z + f23.y * xv.w;
      }
#pragma unroll
      for (int r2 = 0; r2 < 16; ++r2) {
        float v = acc[r2];
        v += __shfl_down(v, 32); v += __shfl_down(v, 16); v += __shfl_down(v, 8);
        v += __shfl_down(v, 4);  v += __shfl_down(v, 2);  v += __shfl_down(v, 1);
        acc[r2] = v;
      }
      if (l == 0) {
#pragma unroll
        for (int r2 = 0; r2 < 16; ++r2) rowbuf[(w << 4) + r2] = acc[r2];
      }
      __syncthreads();
      if (tid < 16) {
        float y = 0.f;
#pragma unroll
        for (int w2 = 0; w2 < 16; ++w2) y += rowbuf[(w2 << 4) + tid];
        const float xo = xc_cur[(blk << 4) + tid];
        xc_nxt[(blk << 4) + tid] = xo + (bcl[tid] - y) * wdiag[tid];
      }
      float* tmp = (float*)xc_cur; xc_cur = xc_nxt; xc_nxt = tmp;
      grid.sync();
    }
    // ---- prolongation ----
    {
      float* xw = (float*)xr;
      const float corr = pvg.x * xc_cur[pcg.x] + pvg.y * xc_cur[pcg.y] +
                         pvg.z * xc_cur[pcg.z] + pvg.w * xc_cur[pcg.w];
      xw[g] = xr[g] + corr;
      grid.sync();
    }
    // ---- post-smooth x3 ----
    for (int it = 0; it < POST_IT; ++it) {
      float s = 0.f;
#pragma unroll
      for (int j = 0; j < DD; ++j) s += av[j] * xr[ac[j]];
      const float xn = xr[g] + (bg - s) * wdg;
      float* wb = (wi == 0) ? x2 : out;
      wb[g] = xn;
      xr = wb; wi ^= 1;
      if (!(cyc == num - 1 && it == POST_IT - 1)) grid.sync();
    }
  }
}

extern "C" void kernel_launch(void* const* d_in, const int* in_sizes, int n_in,
                              void* d_out, int out_size, void* d_ws, size_t ws_size,
                              hipStream_t stream) {
  (void)in_sizes; (void)n_in; (void)out_size; (void)ws_size;
  const float* b      = (const float*)d_in[0];
  const float* x_in   = (const float*)d_in[1];
  const float* A_vals = (const float*)d_in[2];
  const float* P_vals = (const float*)d_in[3];
  const int*   A_cols = (const int*)d_in[4];
  const int*   P_cols = (const int*)d_in[5];
  const int*   num_p  = (const int*)d_in[6];
  float* out = (float*)d_out;

  char* ws = (char*)d_ws;
  unsigned* cnt    = (unsigned*)(ws + 0);                        // 16 KB (becomes cursor)
  unsigned* offs   = (unsigned*)(ws + 16384);                    // 4097 u32
  float*    xcA    = (float*)(ws + 40960);                       // 16 KB
  float*    xcB    = (float*)(ws + 57344);                       // 16 KB
  uint2*    pairs8 = (uint2*)(ws + 73728);                       // 8 MB
  uint4*    Ppack  = (uint4*)(ws + 73728 + 8388608);             // 4 MB
  unsigned* Y      = (unsigned*)(ws + 73728 + 8388608 + 4194304);// 20 MB (80B x N)
  // partials (4MB) and x2 (1MB) alias Y: Y is dead once the build phase (guarded
  // by a grid.sync) completes, and each launch rebuilds Y from scratch.
  float* partials  = (float*)Y;
  float* x2        = (float*)((char*)Y + 4194304);

  hipMemsetAsync(cnt, 0, NCC * sizeof(unsigned), stream);
  hipLaunchKernelGGL(k_hist,    dim3(64),  dim3(1024), 0, stream,
                     (const int4*)P_cols, (const float4*)P_vals, cnt, Ppack);
  hipLaunchKernelGGL(k_scan,    dim3(1),   dim3(1024), 0, stream, cnt, offs);
  hipLaunchKernelGGL(k_scatter, dim3(64),  dim3(1024), 0, stream,
                     (const int4*)P_cols, (const float4*)P_vals, cnt, pairs8);
  hipLaunchKernelGGL(k_buildY,  dim3(256), dim3(1024), 0, stream,
                     A_vals, A_cols, (const uint4*)Ppack, Y);

  const unsigned smem_bytes = 131072 + 16384 + 64 + 64;          // 147584 B < 160 KB
  hipFuncSetAttribute((const void*)k_mega,
                      hipFuncAttributeMaxDynamicSharedMemorySize, (int)smem_bytes);
  void* args[] = { (void*)&b, (void*)&x_in, (void*)&A_vals, (void*)&P_vals,
                   (void*)&A_cols, (void*)&P_cols, (void*)&num_p,
                   (void*)&offs, (void*)&pairs8, (void*)&Y,
                   (void*)&partials, (void*)&x2,
                   (void*)&xcA, (void*)&xcB, (void*)&out };
  hipLaunchCooperativeKernel((void*)k_mega, dim3(256), dim3(1024), args, smem_bytes, stream);
}

// Round 3
// 1117.194 us; speedup vs baseline: 1.2982x; 1.2982x over previous
//
#include <hip/hip_runtime.h>
#include <hip/hip_fp16.h>

#define NN 262144
#define NCC 4096
#define DD 5
#define KK 4
#define PRE_IT 3
#define POST_IT 3
#define COARSE_IT 10
#define WJ ((float)(2.0/3.0))
#define NBLK 256

__device__ __forceinline__ unsigned pack_ch(unsigned col, float v) {
  return col | ((unsigned)__half_as_ushort(__float2half(v)) << 16);
}
__device__ __forceinline__ float unpack_h(unsigned w) {
  return __half2float(__ushort_as_half((unsigned short)(w >> 16)));
}

// ---- lightweight grid barrier: monotone slot counters, one atomic per block ----
// bar[] must be zeroed before launch. Slot k is used exactly once per launch.
__device__ __forceinline__ void gbar(unsigned* __restrict__ bar, int& bs) {
  __syncthreads();                 // all block stores issued (vmcnt drained by barrier)
  if (threadIdx.x == 0) {
    unsigned* c = bar + bs;
    __threadfence();               // release: L2 writeback so other XCDs can see our x writes
    __hip_atomic_fetch_add(c, 1u, __ATOMIC_RELAXED, __HIP_MEMORY_SCOPE_AGENT);
    while (__hip_atomic_load(c, __ATOMIC_RELAXED, __HIP_MEMORY_SCOPE_AGENT) < (unsigned)NBLK) {
      __builtin_amdgcn_s_sleep(1);
    }
    __threadfence();               // acquire: invalidate L1/L2 so we see other XCDs' writes
  }
  ++bs;
  __syncthreads();
}

// ---------------- histogram of P_cols over NC buckets + pack P rows to 16B ----------------
__global__ __launch_bounds__(1024) void k_hist(const int4* __restrict__ pc4,
                                               const float4* __restrict__ pv4,
                                               unsigned* __restrict__ cnt,
                                               uint4* __restrict__ Ppack) {
  __shared__ unsigned h[NCC];
  const int tid = threadIdx.x;
  for (int q = tid; q < NCC; q += 1024) h[q] = 0u;
  __syncthreads();
  const int base = blockIdx.x * 4096;
#pragma unroll
  for (int rr = 0; rr < 4; ++rr) {
    const int r = base + rr * 1024 + tid;
    int4 pc = pc4[r];
    float4 pv = pv4[r];
    Ppack[r] = make_uint4(pack_ch((unsigned)pc.x, pv.x), pack_ch((unsigned)pc.y, pv.y),
                          pack_ch((unsigned)pc.z, pv.z), pack_ch((unsigned)pc.w, pv.w));
    atomicAdd(&h[pc.x], 1u); atomicAdd(&h[pc.y], 1u);
    atomicAdd(&h[pc.z], 1u); atomicAdd(&h[pc.w], 1u);
  }
  __syncthreads();
  for (int q = tid; q < NCC; q += 1024) { unsigned v = h[q]; if (v) atomicAdd(&cnt[q], v); }
}

// ---------------- exclusive scan of 4096 counts (single block) ----------------
__global__ __launch_bounds__(1024) void k_scan(unsigned* __restrict__ cnt_cursor,
                                               unsigned* __restrict__ offs) {
  __shared__ unsigned sv[1024];
  const int t = threadIdx.x;
  unsigned c0 = cnt_cursor[t*4+0], c1 = cnt_cursor[t*4+1],
           c2 = cnt_cursor[t*4+2], c3 = cnt_cursor[t*4+3];
  unsigned s = c0 + c1 + c2 + c3;
  sv[t] = s; __syncthreads();
  for (int off = 1; off < 1024; off <<= 1) {
    unsigned v = (t >= off) ? sv[t-off] : 0u;
    __syncthreads();
    sv[t] += v;
    __syncthreads();
  }
  unsigned run = sv[t] - s;
  unsigned o0 = run, o1 = run + c0, o2 = o1 + c1, o3 = o2 + c2;
  offs[t*4+0] = o0; offs[t*4+1] = o1; offs[t*4+2] = o2; offs[t*4+3] = o3;
  cnt_cursor[t*4+0] = o0; cnt_cursor[t*4+1] = o1;
  cnt_cursor[t*4+2] = o2; cnt_cursor[t*4+3] = o3;
  if (t == 1023) offs[4096] = sv[1023];
}

// ---------------- ranked scatter of {fine row, pv} into coarse-row buckets ----------------
__global__ __launch_bounds__(1024) void k_scatter(const int4* __restrict__ pc4,
                                                  const float4* __restrict__ pv4,
                                                  unsigned* __restrict__ cursor,
                                                  uint2* __restrict__ pairs8) {
  __shared__ unsigned h[NCC];
  __shared__ unsigned basec[NCC];
  const int tid = threadIdx.x;
  for (int q = tid; q < NCC; q += 1024) h[q] = 0u;
  __syncthreads();
  const int rbase = blockIdx.x * 4096;
  int4 pc[4]; float4 pv[4];
#pragma unroll
  for (int rr = 0; rr < 4; ++rr) {
    pc[rr] = pc4[rbase + rr * 1024 + tid];
    pv[rr] = pv4[rbase + rr * 1024 + tid];
    atomicAdd(&h[pc[rr].x], 1u); atomicAdd(&h[pc[rr].y], 1u);
    atomicAdd(&h[pc[rr].z], 1u); atomicAdd(&h[pc[rr].w], 1u);
  }
  __syncthreads();
  for (int q = tid; q < NCC; q += 1024) {
    unsigned v = h[q];
    basec[q] = v ? atomicAdd(&cursor[q], v) : 0u;
  }
  __syncthreads();
  for (int q = tid; q < NCC; q += 1024) h[q] = 0u;
  __syncthreads();
#pragma unroll
  for (int rr = 0; rr < 4; ++rr) {
    const unsigned g = (unsigned)(rbase + rr * 1024 + tid);
    unsigned r;
    r = atomicAdd(&h[pc[rr].x], 1u); pairs8[basec[pc[rr].x] + r] = make_uint2(g, __float_as_uint(pv[rr].x));
    r = atomicAdd(&h[pc[rr].y], 1u); pairs8[basec[pc[rr].y] + r] = make_uint2(g, __float_as_uint(pv[rr].y));
    r = atomicAdd(&h[pc[rr].z], 1u); pairs8[basec[pc[rr].z] + r] = make_uint2(g, __float_as_uint(pv[rr].z));
    r = atomicAdd(&h[pc[rr].w], 1u); pairs8[basec[pc[rr].w] + r] = make_uint2(g, __float_as_uint(pv[rr].w));
  }
}

// ---------------- Y = A*P row-wise: 20 packed (u16 col, half val) per fine row (80B) ----------------
__global__ __launch_bounds__(1024) void k_buildY(const float* __restrict__ A_vals,
                                                 const int* __restrict__ A_cols,
                                                 const uint4* __restrict__ Ppack,
                                                 unsigned* __restrict__ Y) {
  const unsigned g = blockIdx.x * 1024u + threadIdx.x;
  int ac[DD]; float av[DD];
#pragma unroll
  for (int j = 0; j < DD; ++j) { ac[j] = A_cols[g*DD+j]; av[j] = A_vals[g*DD+j]; }
  uint4 pr[DD];
#pragma unroll
  for (int j = 0; j < DD; ++j) pr[j] = Ppack[ac[j]];
  uint4* yp = (uint4*)(Y + 20u * g);
#pragma unroll
  for (int j = 0; j < DD; ++j) {
    uint4 o;
    o.x = pack_ch(pr[j].x & 0xffffu, av[j] * unpack_h(pr[j].x));
    o.y = pack_ch(pr[j].y & 0xffffu, av[j] * unpack_h(pr[j].y));
    o.z = pack_ch(pr[j].z & 0xffffu, av[j] * unpack_h(pr[j].z));
    o.w = pack_ch(pr[j].w & 0xffffu, av[j] * unpack_h(pr[j].w));
    yp[j] = o;
  }
}

// ---------------- the whole V-cycle: one cooperative kernel ----------------
__global__ __launch_bounds__(1024, 4) void k_mega(
    const float* __restrict__ b, const float* __restrict__ x_in,
    const float* __restrict__ A_vals, const float* __restrict__ P_vals,
    const int* __restrict__ A_cols, const int* __restrict__ P_cols,
    const int* __restrict__ num_p,
    const unsigned* __restrict__ offs, const uint2* __restrict__ pairs8,
    const unsigned* __restrict__ Y, unsigned* __restrict__ bar,
    float* __restrict__ partials, float* __restrict__ x2,
    float* __restrict__ xcA, float* __restrict__ xcB,
    float* __restrict__ out) {
  extern __shared__ char smem[];
  __half* slab  = (__half*)smem;                           // 131072 B
  float* rowbuf = (float*)(smem + 131072);                 // 16384 B
  float* wdiag  = (float*)(smem + 131072 + 16384);         // 64 B
  float* bcl    = (float*)(smem + 131072 + 16384 + 64);    // 64 B

  const int tid = threadIdx.x;
  const int blk = blockIdx.x;
  const int g = (blk << 10) + tid;
  int bs = 0;   // barrier slot cursor (identical control flow on every block)

  // ---- build phase: coarse rows [blk*16, blk*16+16) ----
  for (int rr = 0; rr < 16; ++rr) {
    const int c1 = (blk << 4) + rr;
    for (int q = tid; q < NCC; q += 1024) rowbuf[q] = 0.f;
    __syncthreads();
    const unsigned p0 = offs[c1], p1 = offs[c1 + 1];
    for (unsigned p = p0 + tid; p < p1; p += 1024) {
      const uint2 e = pairs8[p];
      const float pv = __uint_as_float(e.y);
      const uint4* yp = (const uint4*)(Y + 20u * e.x);
      uint4 v0 = yp[0], v1 = yp[1], v2 = yp[2], v3 = yp[3], v4 = yp[4];
#define SCAT(v) \
      atomicAdd(&rowbuf[v.x & 0xffffu], pv * unpack_h(v.x)); \
      atomicAdd(&rowbuf[v.y & 0xffffu], pv * unpack_h(v.y)); \
      atomicAdd(&rowbuf[v.z & 0xffffu], pv * unpack_h(v.z)); \
      atomicAdd(&rowbuf[v.w & 0xffffu], pv * unpack_h(v.w));
      SCAT(v0); SCAT(v1); SCAT(v2); SCAT(v3); SCAT(v4);
#undef SCAT
    }
    __syncthreads();
    if (tid == 0) wdiag[rr] = WJ / rowbuf[c1];
    for (int q = tid; q < NCC; q += 1024) slab[(rr << 12) + q] = __float2half(rowbuf[q]);
    __syncthreads();
  }
  gbar(bar, bs);   // Y is dead after this; partials/x2 alias its storage

  const int num = num_p[0];
  if (num <= 0) { out[g] = x_in[g]; return; }

  float av[DD]; int ac[DD];
#pragma unroll
  for (int j = 0; j < DD; ++j) { av[j] = A_vals[g * DD + j]; ac[j] = A_cols[g * DD + j]; }
  const float bg = b[g];
  const float wdg = WJ / av[0];
  const int4 pcg = ((const int4*)P_cols)[g];
  const float4 pvg = ((const float4*)P_vals)[g];

  const float* xr = x_in;
  int wi = 0;

  for (int cyc = 0; cyc < num; ++cyc) {
    // ---- pre-smooth x3 ----
    for (int it = 0; it < PRE_IT; ++it) {
      float s = 0.f;
#pragma unroll
      for (int j = 0; j < DD; ++j) s += av[j] * xr[ac[j]];
      const float xn = xr[g] + (bg - s) * wdg;
      float* wb = (wi == 0) ? x2 : out;
      wb[g] = xn;
      xr = wb; wi ^= 1;
      gbar(bar, bs);
    }
    // ---- residual + block-partial restriction ----
    {
      float s = 0.f;
#pragma unroll
      for (int j = 0; j < DD; ++j) s += av[j] * xr[ac[j]];
      const float r = bg - s;
      for (int q = tid; q < NCC; q += 1024) rowbuf[q] = 0.f;
      __syncthreads();
      atomicAdd(&rowbuf[pcg.x], pvg.x * r);
      atomicAdd(&rowbuf[pcg.y], pvg.y * r);
      atomicAdd(&rowbuf[pcg.z], pvg.z * r);
      atomicAdd(&rowbuf[pcg.w], pvg.w * r);
      __syncthreads();
      for (int q = tid; q < NCC; q += 1024) partials[(blk << 12) + q] = rowbuf[q];
      gbar(bar, bs);
    }
    // ---- reduce partials -> bc + coarse iteration 0 ----
    {
      for (int q = tid; q < 4096; q += 1024) {
        const int t2 = q >> 4, c = q & 15;
        rowbuf[q] = partials[(t2 << 12) + (blk << 4) + c];
      }
      __syncthreads();
      if (tid < 16) {
        float sum = 0.f;
#pragma unroll 8
        for (int t2 = 0; t2 < 256; ++t2) sum += rowbuf[(t2 << 4) + tid];
        bcl[tid] = sum;
        xcA[(blk << 4) + tid] = sum * wdiag[tid];
      }
      gbar(bar, bs);
    }
    // ---- coarse Jacobi iterations 1..9 (LDS-resident fp16 Ac) ----
    const float* xc_cur = xcA;
    float* xc_nxt = xcB;
    for (int it = 1; it < COARSE_IT; ++it) {
      const int w = tid >> 6, l = tid & 63;
      const float4 xv = ((const float4*)xc_cur)[(w << 6) + l];
      float acc[16];
#pragma unroll
      for (int r2 = 0; r2 < 16; ++r2) {
        const __half2* hp2 = (const __half2*)(slab + (r2 << 12) + (w << 8) + (l << 2));
        const float2 f01 = __half22float2(hp2[0]);
        const float2 f23 = __half22float2(hp2[1]);
        acc[r2] = f01.x * xv.x + f01.y * xv.y + f23.x * xv.z + f23.y * xv.w;
      }
#pragma unroll
      for (int r2 = 0; r2 < 16; ++r2) {
        float v = acc[r2];
        v += __shfl_down(v, 32); v += __shfl_down(v, 16); v += __shfl_down(v, 8);
        v += __shfl_down(v, 4);  v += __shfl_down(v, 2);  v += __shfl_down(v, 1);
        acc[r2] = v;
      }
      if (l == 0) {
#pragma unroll
        for (int r2 = 0; r2 < 16; ++r2) rowbuf[(w << 4) + r2] = acc[r2];
      }
      __syncthreads();
      if (tid < 16) {
        float y = 0.f;
#pragma unroll
        for (int w2 = 0; w2 < 16; ++w2) y += rowbuf[(w2 << 4) + tid];
        const float xo = xc_cur[(blk << 4) + tid];
        xc_nxt[(blk << 4) + tid] = xo + (bcl[tid] - y) * wdiag[tid];
      }
      float* tmp = (float*)xc_cur; xc_cur = xc_nxt; xc_nxt = tmp;
      gbar(bar, bs);
    }
    // ---- prolongation ----
    {
      float* xw = (float*)xr;
      const float corr = pvg.x * xc_cur[pcg.x] + pvg.y * xc_cur[pcg.y] +
                         pvg.z * xc_cur[pcg.z] + pvg.w * xc_cur[pcg.w];
      xw[g] = xr[g] + corr;
      gbar(bar, bs);
    }
    // ---- post-smooth x3 ----
    for (int it = 0; it < POST_IT; ++it) {
      float s = 0.f;
#pragma unroll
      for (int j = 0; j < DD; ++j) s += av[j] * xr[ac[j]];
      const float xn = xr[g] + (bg - s) * wdg;
      float* wb = (wi == 0) ? x2 : out;
      wb[g] = xn;
      xr = wb; wi ^= 1;
      if (!(cyc == num - 1 && it == POST_IT - 1)) gbar(bar, bs);
    }
  }
}

extern "C" void kernel_launch(void* const* d_in, const int* in_sizes, int n_in,
                              void* d_out, int out_size, void* d_ws, size_t ws_size,
                              hipStream_t stream) {
  (void)in_sizes; (void)n_in; (void)out_size; (void)ws_size;
  const float* b      = (const float*)d_in[0];
  const float* x_in   = (const float*)d_in[1];
  const float* A_vals = (const float*)d_in[2];
  const float* P_vals = (const float*)d_in[3];
  const int*   A_cols = (const int*)d_in[4];
  const int*   P_cols = (const int*)d_in[5];
  const int*   num_p  = (const int*)d_in[6];
  float* out = (float*)d_out;

  char* ws = (char*)d_ws;
  unsigned* cnt    = (unsigned*)(ws + 0);                        // 16 KB (becomes cursor)
  unsigned* bar    = (unsigned*)(ws + 16384);                    // 2 KB (512 barrier slots)
  unsigned* offs   = (unsigned*)(ws + 18432);                    // 4097 u32
  float*    xcA    = (float*)(ws + 36864);                       // 16 KB
  float*    xcB    = (float*)(ws + 53248);                       // 16 KB
  uint2*    pairs8 = (uint2*)(ws + 73728);                       // 8 MB
  uint4*    Ppack  = (uint4*)(ws + 73728 + 8388608);             // 4 MB
  unsigned* Y      = (unsigned*)(ws + 73728 + 8388608 + 4194304);// 20 MB (80B x N)
  // partials (4MB) and x2 (1MB) alias Y: Y is dead once the build phase (guarded
  // by gbar) completes, and each launch rebuilds Y from scratch.
  float* partials  = (float*)Y;
  float* x2        = (float*)((char*)Y + 4194304);

  hipMemsetAsync(ws, 0, 18432, stream);   // cnt + bar slots
  hipLaunchKernelGGL(k_hist,    dim3(64),  dim3(1024), 0, stream,
                     (const int4*)P_cols, (const float4*)P_vals, cnt, Ppack);
  hipLaunchKernelGGL(k_scan,    dim3(1),   dim3(1024), 0, stream, cnt, offs);
  hipLaunchKernelGGL(k_scatter, dim3(64),  dim3(1024), 0, stream,
                     (const int4*)P_cols, (const float4*)P_vals, cnt, pairs8);
  hipLaunchKernelGGL(k_buildY,  dim3(256), dim3(1024), 0, stream,
                     A_vals, A_cols, (const uint4*)Ppack, Y);

  const unsigned smem_bytes = 131072 + 16384 + 64 + 64;          // 147584 B < 160 KB
  hipFuncSetAttribute((const void*)k_mega,
                      hipFuncAttributeMaxDynamicSharedMemorySize, (int)smem_bytes);
  void* args[] = { (void*)&b, (void*)&x_in, (void*)&A_vals, (void*)&P_vals,
                   (void*)&A_cols, (void*)&P_cols, (void*)&num_p,
                   (void*)&offs, (void*)&pairs8, (void*)&Y, (void*)&bar,
                   (void*)&partials, (void*)&x2,
                   (void*)&xcA, (void*)&xcB, (void*)&out };
  hipLaunchCooperativeKernel((void*)k_mega, dim3(256), dim3(1024), args, smem_bytes, stream);
}

// Round 4
// 923.525 us; speedup vs baseline: 1.5705x; 1.2097x over previous
//
#include <hip/hip_runtime.h>
#include <hip/hip_fp16.h>

#define NN 262144
#define NCC 4096
#define DD 5
#define KK 4
#define PRE_IT 3
#define POST_IT 3
#define COARSE_IT 10
#define WJ ((float)(2.0/3.0))
#define NBLK 256
#define BAR_SLOT_U32 288   // 16 leaf lines (16 u32 apart) + root line + flag line = 1152 B

__device__ __forceinline__ unsigned pack_ch(unsigned col, float v) {
  return col | ((unsigned)__half_as_ushort(__float2half(v)) << 16);
}
__device__ __forceinline__ float unpack_h(unsigned w) {
  return __half2float(__ushort_as_half((unsigned short)(w >> 16)));
}

// ---- 2-level tree grid barrier: 16 leaf lines + root line + flag line per slot ----
// bar[] zeroed before launch; slot bs used exactly once per launch (monotone cursor).
// Arrival RMWs spread over 16 independent cache lines (max 16 serialized RMWs/line);
// completion broadcast on a separate read-only flag line (no RMW/poll interference).
__device__ __forceinline__ void gbar(unsigned* __restrict__ bar, int& bs) {
  __syncthreads();
  if (threadIdx.x == 0) {
    unsigned* slot = bar + bs * BAR_SLOT_U32;
    unsigned* leaf = slot + ((blockIdx.x >> 4) << 4);   // own 64B line per group
    unsigned* root = slot + 256;
    unsigned* flag = slot + 272;
    __threadfence();   // release: our payload visible before our arrival
    unsigned r = __hip_atomic_fetch_add(leaf, 1u, __ATOMIC_RELAXED, __HIP_MEMORY_SCOPE_AGENT);
    if (r == 15u) {    // last of 16 in group
      __threadfence(); // acquire peers' payload / release for root hop
      unsigned r2 = __hip_atomic_fetch_add(root, 1u, __ATOMIC_RELAXED, __HIP_MEMORY_SCOPE_AGENT);
      if (r2 == 15u) { // last group
        __threadfence();
        __hip_atomic_store(flag, 1u, __ATOMIC_RELAXED, __HIP_MEMORY_SCOPE_AGENT);
      }
    }
    while (__hip_atomic_load(flag, __ATOMIC_RELAXED, __HIP_MEMORY_SCOPE_AGENT) == 0u) {
      __builtin_amdgcn_s_sleep(1);
    }
    __threadfence();   // acquire: everyone's payload visible to this block
  }
  ++bs;
  __syncthreads();
}

// ---------------- histogram of P_cols over NC buckets + pack P rows to 16B ----------------
__global__ __launch_bounds__(1024) void k_hist(const int4* __restrict__ pc4,
                                               const float4* __restrict__ pv4,
                                               unsigned* __restrict__ cnt,
                                               uint4* __restrict__ Ppack) {
  __shared__ unsigned h[NCC];
  const int tid = threadIdx.x;
  for (int q = tid; q < NCC; q += 1024) h[q] = 0u;
  __syncthreads();
  const int base = blockIdx.x * 4096;
#pragma unroll
  for (int rr = 0; rr < 4; ++rr) {
    const int r = base + rr * 1024 + tid;
    int4 pc = pc4[r];
    float4 pv = pv4[r];
    Ppack[r] = make_uint4(pack_ch((unsigned)pc.x, pv.x), pack_ch((unsigned)pc.y, pv.y),
                          pack_ch((unsigned)pc.z, pv.z), pack_ch((unsigned)pc.w, pv.w));
    atomicAdd(&h[pc.x], 1u); atomicAdd(&h[pc.y], 1u);
    atomicAdd(&h[pc.z], 1u); atomicAdd(&h[pc.w], 1u);
  }
  __syncthreads();
  for (int q = tid; q < NCC; q += 1024) { unsigned v = h[q]; if (v) atomicAdd(&cnt[q], v); }
}

// ---------------- exclusive scan of 4096 counts (single block) ----------------
__global__ __launch_bounds__(1024) void k_scan(unsigned* __restrict__ cnt_cursor,
                                               unsigned* __restrict__ offs) {
  __shared__ unsigned sv[1024];
  const int t = threadIdx.x;
  unsigned c0 = cnt_cursor[t*4+0], c1 = cnt_cursor[t*4+1],
           c2 = cnt_cursor[t*4+2], c3 = cnt_cursor[t*4+3];
  unsigned s = c0 + c1 + c2 + c3;
  sv[t] = s; __syncthreads();
  for (int off = 1; off < 1024; off <<= 1) {
    unsigned v = (t >= off) ? sv[t-off] : 0u;
    __syncthreads();
    sv[t] += v;
    __syncthreads();
  }
  unsigned run = sv[t] - s;
  unsigned o0 = run, o1 = run + c0, o2 = o1 + c1, o3 = o2 + c2;
  offs[t*4+0] = o0; offs[t*4+1] = o1; offs[t*4+2] = o2; offs[t*4+3] = o3;
  cnt_cursor[t*4+0] = o0; cnt_cursor[t*4+1] = o1;
  cnt_cursor[t*4+2] = o2; cnt_cursor[t*4+3] = o3;
  if (t == 1023) offs[4096] = sv[1023];
}

// ---------------- ranked scatter of {fine row, pv} into coarse-row buckets ----------------
__global__ __launch_bounds__(1024) void k_scatter(const int4* __restrict__ pc4,
                                                  const float4* __restrict__ pv4,
                                                  unsigned* __restrict__ cursor,
                                                  uint2* __restrict__ pairs8) {
  __shared__ unsigned h[NCC];
  __shared__ unsigned basec[NCC];
  const int tid = threadIdx.x;
  for (int q = tid; q < NCC; q += 1024) h[q] = 0u;
  __syncthreads();
  const int rbase = blockIdx.x * 4096;
  int4 pc[4]; float4 pv[4];
#pragma unroll
  for (int rr = 0; rr < 4; ++rr) {
    pc[rr] = pc4[rbase + rr * 1024 + tid];
    pv[rr] = pv4[rbase + rr * 1024 + tid];
    atomicAdd(&h[pc[rr].x], 1u); atomicAdd(&h[pc[rr].y], 1u);
    atomicAdd(&h[pc[rr].z], 1u); atomicAdd(&h[pc[rr].w], 1u);
  }
  __syncthreads();
  for (int q = tid; q < NCC; q += 1024) {
    unsigned v = h[q];
    basec[q] = v ? atomicAdd(&cursor[q], v) : 0u;
  }
  __syncthreads();
  for (int q = tid; q < NCC; q += 1024) h[q] = 0u;
  __syncthreads();
#pragma unroll
  for (int rr = 0; rr < 4; ++rr) {
    const unsigned g = (unsigned)(rbase + rr * 1024 + tid);
    unsigned r;
    r = atomicAdd(&h[pc[rr].x], 1u); pairs8[basec[pc[rr].x] + r] = make_uint2(g, __float_as_uint(pv[rr].x));
    r = atomicAdd(&h[pc[rr].y], 1u); pairs8[basec[pc[rr].y] + r] = make_uint2(g, __float_as_uint(pv[rr].y));
    r = atomicAdd(&h[pc[rr].z], 1u); pairs8[basec[pc[rr].z] + r] = make_uint2(g, __float_as_uint(pv[rr].z));
    r = atomicAdd(&h[pc[rr].w], 1u); pairs8[basec[pc[rr].w] + r] = make_uint2(g, __float_as_uint(pv[rr].w));
  }
}

// ---------------- Y = A*P row-wise: 20 packed (u16 col, half val) per fine row (80B) ----------------
__global__ __launch_bounds__(1024) void k_buildY(const float* __restrict__ A_vals,
                                                 const int* __restrict__ A_cols,
                                                 const uint4* __restrict__ Ppack,
                                                 unsigned* __restrict__ Y) {
  const unsigned g = blockIdx.x * 1024u + threadIdx.x;
  int ac[DD]; float av[DD];
#pragma unroll
  for (int j = 0; j < DD; ++j) { ac[j] = A_cols[g*DD+j]; av[j] = A_vals[g*DD+j]; }
  uint4 pr[DD];
#pragma unroll
  for (int j = 0; j < DD; ++j) pr[j] = Ppack[ac[j]];
  uint4* yp = (uint4*)(Y + 20u * g);
#pragma unroll
  for (int j = 0; j < DD; ++j) {
    uint4 o;
    o.x = pack_ch(pr[j].x & 0xffffu, av[j] * unpack_h(pr[j].x));
    o.y = pack_ch(pr[j].y & 0xffffu, av[j] * unpack_h(pr[j].y));
    o.z = pack_ch(pr[j].z & 0xffffu, av[j] * unpack_h(pr[j].z));
    o.w = pack_ch(pr[j].w & 0xffffu, av[j] * unpack_h(pr[j].w));
    yp[j] = o;
  }
}

// ---------------- the whole V-cycle: one cooperative kernel ----------------
__global__ __launch_bounds__(1024, 4) void k_mega(
    const float* __restrict__ b, const float* __restrict__ x_in,
    const float* __restrict__ A_vals, const float* __restrict__ P_vals,
    const int* __restrict__ A_cols, const int* __restrict__ P_cols,
    const int* __restrict__ num_p,
    const unsigned* __restrict__ offs, const uint2* __restrict__ pairs8,
    const unsigned* __restrict__ Y, unsigned* __restrict__ bar,
    float* __restrict__ partials, float* __restrict__ x2,
    float* __restrict__ xcA, float* __restrict__ xcB,
    float* __restrict__ out) {
  extern __shared__ char smem[];
  __half* slab  = (__half*)smem;                           // 131072 B
  float* rowbuf = (float*)(smem + 131072);                 // 16384 B
  float* wdiag  = (float*)(smem + 131072 + 16384);         // 64 B
  float* bcl    = (float*)(smem + 131072 + 16384 + 64);    // 64 B

  const int tid = threadIdx.x;
  const int blk = blockIdx.x;
  const int g = (blk << 10) + tid;
  int bs = 0;   // barrier slot cursor (identical control flow on every block)

  // ---- build phase: coarse rows [blk*16, blk*16+16) ----
  for (int rr = 0; rr < 16; ++rr) {
    const int c1 = (blk << 4) + rr;
    for (int q = tid; q < NCC; q += 1024) rowbuf[q] = 0.f;
    __syncthreads();
    const unsigned p0 = offs[c1], p1 = offs[c1 + 1];
    for (unsigned p = p0 + tid; p < p1; p += 1024) {
      const uint2 e = pairs8[p];
      const float pv = __uint_as_float(e.y);
      const uint4* yp = (const uint4*)(Y + 20u * e.x);
      uint4 v0 = yp[0], v1 = yp[1], v2 = yp[2], v3 = yp[3], v4 = yp[4];
#define SCAT(v) \
      atomicAdd(&rowbuf[v.x & 0xffffu], pv * unpack_h(v.x)); \
      atomicAdd(&rowbuf[v.y & 0xffffu], pv * unpack_h(v.y)); \
      atomicAdd(&rowbuf[v.z & 0xffffu], pv * unpack_h(v.z)); \
      atomicAdd(&rowbuf[v.w & 0xffffu], pv * unpack_h(v.w));
      SCAT(v0); SCAT(v1); SCAT(v2); SCAT(v3); SCAT(v4);
#undef SCAT
    }
    __syncthreads();
    if (tid == 0) wdiag[rr] = WJ / rowbuf[c1];
    for (int q = tid; q < NCC; q += 1024) slab[(rr << 12) + q] = __float2half(rowbuf[q]);
    __syncthreads();
  }
  gbar(bar, bs);   // Y is dead after this; partials/x2 alias its storage

  const int num = num_p[0];
  if (num <= 0) { out[g] = x_in[g]; return; }

  float av[DD]; int ac[DD];
#pragma unroll
  for (int j = 0; j < DD; ++j) { av[j] = A_vals[g * DD + j]; ac[j] = A_cols[g * DD + j]; }
  const float bg = b[g];
  const float wdg = WJ / av[0];
  const int4 pcg = ((const int4*)P_cols)[g];
  const float4 pvg = ((const float4*)P_vals)[g];

  const float* xr = x_in;
  int wi = 0;

  for (int cyc = 0; cyc < num; ++cyc) {
    // ---- pre-smooth x3 ----
    for (int it = 0; it < PRE_IT; ++it) {
      float s = 0.f;
#pragma unroll
      for (int j = 0; j < DD; ++j) s += av[j] * xr[ac[j]];
      const float xn = xr[g] + (bg - s) * wdg;
      float* wb = (wi == 0) ? x2 : out;
      wb[g] = xn;
      xr = wb; wi ^= 1;
      gbar(bar, bs);
    }
    // ---- residual + block-partial restriction ----
    {
      float s = 0.f;
#pragma unroll
      for (int j = 0; j < DD; ++j) s += av[j] * xr[ac[j]];
      const float r = bg - s;
      for (int q = tid; q < NCC; q += 1024) rowbuf[q] = 0.f;
      __syncthreads();
      atomicAdd(&rowbuf[pcg.x], pvg.x * r);
      atomicAdd(&rowbuf[pcg.y], pvg.y * r);
      atomicAdd(&rowbuf[pcg.z], pvg.z * r);
      atomicAdd(&rowbuf[pcg.w], pvg.w * r);
      __syncthreads();
      for (int q = tid; q < NCC; q += 1024) partials[(blk << 12) + q] = rowbuf[q];
      gbar(bar, bs);
    }
    // ---- reduce partials -> bc + coarse iteration 0 ----
    {
      for (int q = tid; q < 4096; q += 1024) {
        const int t2 = q >> 4, c = q & 15;
        rowbuf[q] = partials[(t2 << 12) + (blk << 4) + c];
      }
      __syncthreads();
      if (tid < 16) {
        float sum = 0.f;
#pragma unroll 8
        for (int t2 = 0; t2 < 256; ++t2) sum += rowbuf[(t2 << 4) + tid];
        bcl[tid] = sum;
        xcA[(blk << 4) + tid] = sum * wdiag[tid];
      }
      gbar(bar, bs);
    }
    // ---- coarse Jacobi iterations 1..9 (LDS-resident fp16 Ac) ----
    const float* xc_cur = xcA;
    float* xc_nxt = xcB;
    for (int it = 1; it < COARSE_IT; ++it) {
      const int w = tid >> 6, l = tid & 63;
      const float4 xv = ((const float4*)xc_cur)[(w << 6) + l];
      float acc[16];
#pragma unroll
      for (int r2 = 0; r2 < 16; ++r2) {
        const __half2* hp2 = (const __half2*)(slab + (r2 << 12) + (w << 8) + (l << 2));
        const float2 f01 = __half22float2(hp2[0]);
        const float2 f23 = __half22float2(hp2[1]);
        acc[r2] = f01.x * xv.x + f01.y * xv.y + f23.x * xv.z + f23.y * xv.w;
      }
#pragma unroll
      for (int r2 = 0; r2 < 16; ++r2) {
        float v = acc[r2];
        v += __shfl_down(v, 32); v += __shfl_down(v, 16); v += __shfl_down(v, 8);
        v += __shfl_down(v, 4);  v += __shfl_down(v, 2);  v += __shfl_down(v, 1);
        acc[r2] = v;
      }
      if (l == 0) {
#pragma unroll
        for (int r2 = 0; r2 < 16; ++r2) rowbuf[(w << 4) + r2] = acc[r2];
      }
      __syncthreads();
      if (tid < 16) {
        float y = 0.f;
#pragma unroll
        for (int w2 = 0; w2 < 16; ++w2) y += rowbuf[(w2 << 4) + tid];
        const float xo = xc_cur[(blk << 4) + tid];
        xc_nxt[(blk << 4) + tid] = xo + (bcl[tid] - y) * wdiag[tid];
      }
      float* tmp = (float*)xc_cur; xc_cur = xc_nxt; xc_nxt = tmp;
      gbar(bar, bs);
    }
    // ---- prolongation ----
    {
      float* xw = (float*)xr;
      const float corr = pvg.x * xc_cur[pcg.x] + pvg.y * xc_cur[pcg.y] +
                         pvg.z * xc_cur[pcg.z] + pvg.w * xc_cur[pcg.w];
      xw[g] = xr[g] + corr;
      gbar(bar, bs);
    }
    // ---- post-smooth x3 ----
    for (int it = 0; it < POST_IT; ++it) {
      float s = 0.f;
#pragma unroll
      for (int j = 0; j < DD; ++j) s += av[j] * xr[ac[j]];
      const float xn = xr[g] + (bg - s) * wdg;
      float* wb = (wi == 0) ? x2 : out;
      wb[g] = xn;
      xr = wb; wi ^= 1;
      if (!(cyc == num - 1 && it == POST_IT - 1)) gbar(bar, bs);
    }
  }
}

extern "C" void kernel_launch(void* const* d_in, const int* in_sizes, int n_in,
                              void* d_out, int out_size, void* d_ws, size_t ws_size,
                              hipStream_t stream) {
  (void)in_sizes; (void)n_in; (void)out_size; (void)ws_size;
  const float* b      = (const float*)d_in[0];
  const float* x_in   = (const float*)d_in[1];
  const float* A_vals = (const float*)d_in[2];
  const float* P_vals = (const float*)d_in[3];
  const int*   A_cols = (const int*)d_in[4];
  const int*   P_cols = (const int*)d_in[5];
  const int*   num_p  = (const int*)d_in[6];
  float* out = (float*)d_out;

  char* ws = (char*)d_ws;
  unsigned* cnt    = (unsigned*)(ws + 0);                        // 16 KB (becomes cursor)
  unsigned* offs   = (unsigned*)(ws + 16384);                    // 4097 u32
  float*    xcA    = (float*)(ws + 36864);                       // 16 KB
  float*    xcB    = (float*)(ws + 53248);                       // 16 KB
  unsigned* bar    = (unsigned*)(ws + 69632);                    // 160 slots x 1152 B = 184320 B
  uint2*    pairs8 = (uint2*)(ws + 262144);                      // 8 MB
  uint4*    Ppack  = (uint4*)(ws + 262144 + 8388608);            // 4 MB
  unsigned* Y      = (unsigned*)(ws + 262144 + 8388608 + 4194304);// 20 MB (80B x N)
  // partials (4MB) and x2 (1MB) alias Y: Y is dead once the build phase (guarded
  // by gbar) completes, and each launch rebuilds Y from scratch.
  float* partials  = (float*)Y;
  float* x2        = (float*)((char*)Y + 4194304);

  hipMemsetAsync(cnt, 0, NCC * sizeof(unsigned), stream);
  hipMemsetAsync(bar, 0, 160 * BAR_SLOT_U32 * sizeof(unsigned), stream);
  hipLaunchKernelGGL(k_hist,    dim3(64),  dim3(1024), 0, stream,
                     (const int4*)P_cols, (const float4*)P_vals, cnt, Ppack);
  hipLaunchKernelGGL(k_scan,    dim3(1),   dim3(1024), 0, stream, cnt, offs);
  hipLaunchKernelGGL(k_scatter, dim3(64),  dim3(1024), 0, stream,
                     (const int4*)P_cols, (const float4*)P_vals, cnt, pairs8);
  hipLaunchKernelGGL(k_buildY,  dim3(256), dim3(1024), 0, stream,
                     A_vals, A_cols, (const uint4*)Ppack, Y);

  const unsigned smem_bytes = 131072 + 16384 + 64 + 64;          // 147584 B < 160 KB
  hipFuncSetAttribute((const void*)k_mega,
                      hipFuncAttributeMaxDynamicSharedMemorySize, (int)smem_bytes);
  void* args[] = { (void*)&b, (void*)&x_in, (void*)&A_vals, (void*)&P_vals,
                   (void*)&A_cols, (void*)&P_cols, (void*)&num_p,
                   (void*)&offs, (void*)&pairs8, (void*)&Y, (void*)&bar,
                   (void*)&partials, (void*)&x2,
                   (void*)&xcA, (void*)&xcB, (void*)&out };
  hipLaunchCooperativeKernel((void*)k_mega, dim3(256), dim3(1024), args, smem_bytes, stream);
}

// Round 5
// 623.908 us; speedup vs baseline: 2.3246x; 1.4802x over previous
//
#include <hip/hip_runtime.h>
#include <hip/hip_fp16.h>

#define NN 262144
#define NCC 4096
#define DD 5
#define KK 4
#define PRE_IT 3
#define POST_IT 3
#define COARSE_IT 10
#define WJ ((float)(2.0/3.0))
#define NBLK 256
#define BAR_SLOT_U32 288   // 16 leaf lines (16 u32 apart) + root line + flag line = 1152 B

__device__ __forceinline__ unsigned pack_ch(unsigned col, float v) {
  return col | ((unsigned)__half_as_ushort(__float2half(v)) << 16);
}
__device__ __forceinline__ float unpack_h(unsigned w) {
  return __half2float(__ushort_as_half((unsigned short)(w >> 16)));
}

// Device-coherent (agent-scope, L3 coherence point) scalar accesses: emit sc0/sc1
// VMEM ops that bypass the non-coherent per-XCD L2s. All cross-block payload in
// k_mega uses these, which lets the grid barrier drop its L2 wb/inv fences.
__device__ __forceinline__ float ldA(const float* p) {
  return __hip_atomic_load((const float*)p, __ATOMIC_RELAXED, __HIP_MEMORY_SCOPE_AGENT);
}
__device__ __forceinline__ void stA(float* p, float v) {
  __hip_atomic_store(p, v, __ATOMIC_RELAXED, __HIP_MEMORY_SCOPE_AGENT);
}

// ---- fence-free 2-level tree grid barrier ----
// Validity: __syncthreads() drains each wave's vmcnt; sc1 stores ack from the
// coherence point, so at arrival every payload store is visible at L3. Consumers
// read payload with sc1 loads (bypass stale L2), so no buffer_wbl2/inv needed.
__device__ __forceinline__ void gbar(unsigned* __restrict__ bar, int& bs) {
  __syncthreads();
  if (threadIdx.x == 0) {
    unsigned* slot = bar + bs * BAR_SLOT_U32;
    unsigned* leaf = slot + ((blockIdx.x >> 4) << 4);   // own 64B line per 16-block group
    unsigned* root = slot + 256;
    unsigned* flag = slot + 272;
    unsigned r = __hip_atomic_fetch_add(leaf, 1u, __ATOMIC_RELAXED, __HIP_MEMORY_SCOPE_AGENT);
    if (r == 15u) {
      unsigned r2 = __hip_atomic_fetch_add(root, 1u, __ATOMIC_RELAXED, __HIP_MEMORY_SCOPE_AGENT);
      if (r2 == 15u) {
        __hip_atomic_store(flag, 1u, __ATOMIC_RELAXED, __HIP_MEMORY_SCOPE_AGENT);
      }
    }
    while (__hip_atomic_load(flag, __ATOMIC_RELAXED, __HIP_MEMORY_SCOPE_AGENT) == 0u) {
      __builtin_amdgcn_s_sleep(1);
    }
  }
  ++bs;
  __syncthreads();
}

// ---------------- histogram of P_cols over NC buckets + pack P rows to 16B ----------------
__global__ __launch_bounds__(1024) void k_hist(const int4* __restrict__ pc4,
                                               const float4* __restrict__ pv4,
                                               unsigned* __restrict__ cnt,
                                               uint4* __restrict__ Ppack) {
  __shared__ unsigned h[NCC];
  const int tid = threadIdx.x;
  for (int q = tid; q < NCC; q += 1024) h[q] = 0u;
  __syncthreads();
  const int base = blockIdx.x * 4096;
#pragma unroll
  for (int rr = 0; rr < 4; ++rr) {
    const int r = base + rr * 1024 + tid;
    int4 pc = pc4[r];
    float4 pv = pv4[r];
    Ppack[r] = make_uint4(pack_ch((unsigned)pc.x, pv.x), pack_ch((unsigned)pc.y, pv.y),
                          pack_ch((unsigned)pc.z, pv.z), pack_ch((unsigned)pc.w, pv.w));
    atomicAdd(&h[pc.x], 1u); atomicAdd(&h[pc.y], 1u);
    atomicAdd(&h[pc.z], 1u); atomicAdd(&h[pc.w], 1u);
  }
  __syncthreads();
  for (int q = tid; q < NCC; q += 1024) { unsigned v = h[q]; if (v) atomicAdd(&cnt[q], v); }
}

// ---------------- exclusive scan of 4096 counts (single block) ----------------
__global__ __launch_bounds__(1024) void k_scan(unsigned* __restrict__ cnt_cursor,
                                               unsigned* __restrict__ offs) {
  __shared__ unsigned sv[1024];
  const int t = threadIdx.x;
  unsigned c0 = cnt_cursor[t*4+0], c1 = cnt_cursor[t*4+1],
           c2 = cnt_cursor[t*4+2], c3 = cnt_cursor[t*4+3];
  unsigned s = c0 + c1 + c2 + c3;
  sv[t] = s; __syncthreads();
  for (int off = 1; off < 1024; off <<= 1) {
    unsigned v = (t >= off) ? sv[t-off] : 0u;
    __syncthreads();
    sv[t] += v;
    __syncthreads();
  }
  unsigned run = sv[t] - s;
  unsigned o0 = run, o1 = run + c0, o2 = o1 + c1, o3 = o2 + c2;
  offs[t*4+0] = o0; offs[t*4+1] = o1; offs[t*4+2] = o2; offs[t*4+3] = o3;
  cnt_cursor[t*4+0] = o0; cnt_cursor[t*4+1] = o1;
  cnt_cursor[t*4+2] = o2; cnt_cursor[t*4+3] = o3;
  if (t == 1023) offs[4096] = sv[1023];
}

// ---------------- ranked scatter of {fine row, pv} into coarse-row buckets ----------------
__global__ __launch_bounds__(1024) void k_scatter(const int4* __restrict__ pc4,
                                                  const float4* __restrict__ pv4,
                                                  unsigned* __restrict__ cursor,
                                                  uint2* __restrict__ pairs8) {
  __shared__ unsigned h[NCC];
  __shared__ unsigned basec[NCC];
  const int tid = threadIdx.x;
  for (int q = tid; q < NCC; q += 1024) h[q] = 0u;
  __syncthreads();
  const int rbase = blockIdx.x * 4096;
  int4 pc[4]; float4 pv[4];
#pragma unroll
  for (int rr = 0; rr < 4; ++rr) {
    pc[rr] = pc4[rbase + rr * 1024 + tid];
    pv[rr] = pv4[rbase + rr * 1024 + tid];
    atomicAdd(&h[pc[rr].x], 1u); atomicAdd(&h[pc[rr].y], 1u);
    atomicAdd(&h[pc[rr].z], 1u); atomicAdd(&h[pc[rr].w], 1u);
  }
  __syncthreads();
  for (int q = tid; q < NCC; q += 1024) {
    unsigned v = h[q];
    basec[q] = v ? atomicAdd(&cursor[q], v) : 0u;
  }
  __syncthreads();
  for (int q = tid; q < NCC; q += 1024) h[q] = 0u;
  __syncthreads();
#pragma unroll
  for (int rr = 0; rr < 4; ++rr) {
    const unsigned g = (unsigned)(rbase + rr * 1024 + tid);
    unsigned r;
    r = atomicAdd(&h[pc[rr].x], 1u); pairs8[basec[pc[rr].x] + r] = make_uint2(g, __float_as_uint(pv[rr].x));
    r = atomicAdd(&h[pc[rr].y], 1u); pairs8[basec[pc[rr].y] + r] = make_uint2(g, __float_as_uint(pv[rr].y));
    r = atomicAdd(&h[pc[rr].z], 1u); pairs8[basec[pc[rr].z] + r] = make_uint2(g, __float_as_uint(pv[rr].z));
    r = atomicAdd(&h[pc[rr].w], 1u); pairs8[basec[pc[rr].w] + r] = make_uint2(g, __float_as_uint(pv[rr].w));
  }
}

// ---------------- Y = A*P row-wise: 20 packed (u16 col, half val) per fine row (80B) ----------------
__global__ __launch_bounds__(1024) void k_buildY(const float* __restrict__ A_vals,
                                                 const int* __restrict__ A_cols,
                                                 const uint4* __restrict__ Ppack,
                                                 unsigned* __restrict__ Y) {
  const unsigned g = blockIdx.x * 1024u + threadIdx.x;
  int ac[DD]; float av[DD];
#pragma unroll
  for (int j = 0; j < DD; ++j) { ac[j] = A_cols[g*DD+j]; av[j] = A_vals[g*DD+j]; }
  uint4 pr[DD];
#pragma unroll
  for (int j = 0; j < DD; ++j) pr[j] = Ppack[ac[j]];
  uint4* yp = (uint4*)(Y + 20u * g);
#pragma unroll
  for (int j = 0; j < DD; ++j) {
    uint4 o;
    o.x = pack_ch(pr[j].x & 0xffffu, av[j] * unpack_h(pr[j].x));
    o.y = pack_ch(pr[j].y & 0xffffu, av[j] * unpack_h(pr[j].y));
    o.z = pack_ch(pr[j].z & 0xffffu, av[j] * unpack_h(pr[j].z));
    o.w = pack_ch(pr[j].w & 0xffffu, av[j] * unpack_h(pr[j].w));
    yp[j] = o;
  }
}

// ---------------- the whole V-cycle: one cooperative kernel ----------------
__global__ __launch_bounds__(1024, 4) void k_mega(
    const float* __restrict__ b, const float* __restrict__ x_in,
    const float* __restrict__ A_vals, const float* __restrict__ P_vals,
    const int* __restrict__ A_cols, const int* __restrict__ P_cols,
    const int* __restrict__ num_p,
    const unsigned* __restrict__ offs, const uint2* __restrict__ pairs8,
    const unsigned* __restrict__ Y, unsigned* __restrict__ bar,
    float* __restrict__ partials, float* __restrict__ x2,
    float* __restrict__ xcA, float* __restrict__ xcB,
    float* __restrict__ out) {
  extern __shared__ char smem[];
  __half* slab  = (__half*)smem;                           // 131072 B
  float* rowbuf = (float*)(smem + 131072);                 // 16384 B
  float* wdiag  = (float*)(smem + 131072 + 16384);         // 64 B
  float* bcl    = (float*)(smem + 131072 + 16384 + 64);    // 64 B

  const int tid = threadIdx.x;
  const int blk = blockIdx.x;
  const int g = (blk << 10) + tid;
  int bs = 0;   // barrier slot cursor (identical control flow on every block)

  // ---- build phase: coarse rows [blk*16, blk*16+16) ----
  for (int rr = 0; rr < 16; ++rr) {
    const int c1 = (blk << 4) + rr;
    for (int q = tid; q < NCC; q += 1024) rowbuf[q] = 0.f;
    __syncthreads();
    const unsigned p0 = offs[c1], p1 = offs[c1 + 1];
    for (unsigned p = p0 + tid; p < p1; p += 1024) {
      const uint2 e = pairs8[p];
      const float pv = __uint_as_float(e.y);
      const uint4* yp = (const uint4*)(Y + 20u * e.x);
      uint4 v0 = yp[0], v1 = yp[1], v2 = yp[2], v3 = yp[3], v4 = yp[4];
#define SCAT(v) \
      atomicAdd(&rowbuf[v.x & 0xffffu], pv * unpack_h(v.x)); \
      atomicAdd(&rowbuf[v.y & 0xffffu], pv * unpack_h(v.y)); \
      atomicAdd(&rowbuf[v.z & 0xffffu], pv * unpack_h(v.z)); \
      atomicAdd(&rowbuf[v.w & 0xffffu], pv * unpack_h(v.w));
      SCAT(v0); SCAT(v1); SCAT(v2); SCAT(v3); SCAT(v4);
#undef SCAT
    }
    __syncthreads();
    if (tid == 0) wdiag[rr] = WJ / rowbuf[c1];
    for (int q = tid; q < NCC; q += 1024) slab[(rr << 12) + q] = __float2half(rowbuf[q]);
    __syncthreads();
  }
  gbar(bar, bs);   // Y is dead after this; partials/x2 alias its storage

  const int num = num_p[0];
  if (num <= 0) { out[g] = x_in[g]; return; }

  float av[DD]; int ac[DD];
#pragma unroll
  for (int j = 0; j < DD; ++j) { av[j] = A_vals[g * DD + j]; ac[j] = A_cols[g * DD + j]; }
  const float bg = b[g];
  const float wdg = WJ / av[0];
  const int4 pcg = ((const int4*)P_cols)[g];
  const float4 pvg = ((const float4*)P_vals)[g];

  const float* xr = x_in;
  int wi = 0;

  for (int cyc = 0; cyc < num; ++cyc) {
    // ---- pre-smooth x3 ----
    for (int it = 0; it < PRE_IT; ++it) {
      float s = 0.f;
#pragma unroll
      for (int j = 0; j < DD; ++j) s += av[j] * ldA(xr + ac[j]);
      const float xn = ldA(xr + g) + (bg - s) * wdg;
      float* wb = (wi == 0) ? x2 : out;
      stA(wb + g, xn);
      xr = wb; wi ^= 1;
      gbar(bar, bs);
    }
    // ---- residual + block-partial restriction ----
    {
      float s = 0.f;
#pragma unroll
      for (int j = 0; j < DD; ++j) s += av[j] * ldA(xr + ac[j]);
      const float r = bg - s;
      for (int q = tid; q < NCC; q += 1024) rowbuf[q] = 0.f;
      __syncthreads();
      atomicAdd(&rowbuf[pcg.x], pvg.x * r);
      atomicAdd(&rowbuf[pcg.y], pvg.y * r);
      atomicAdd(&rowbuf[pcg.z], pvg.z * r);
      atomicAdd(&rowbuf[pcg.w], pvg.w * r);
      __syncthreads();
      for (int q = tid; q < NCC; q += 1024) stA(&partials[(blk << 12) + q], rowbuf[q]);
      gbar(bar, bs);
    }
    // ---- reduce partials -> bc + coarse iteration 0 ----
    {
      for (int q = tid; q < 4096; q += 1024) {
        const int t2 = q >> 4, c = q & 15;
        rowbuf[q] = ldA(&partials[(t2 << 12) + (blk << 4) + c]);
      }
      __syncthreads();
      if (tid < 16) {
        float sum = 0.f;
#pragma unroll 8
        for (int t2 = 0; t2 < 256; ++t2) sum += rowbuf[(t2 << 4) + tid];
        bcl[tid] = sum;
        stA(&xcA[(blk << 4) + tid], sum * wdiag[tid]);
      }
      gbar(bar, bs);
    }
    // ---- coarse Jacobi iterations 1..9 (LDS-resident fp16 Ac) ----
    const float* xc_cur = xcA;
    float* xc_nxt = xcB;
    for (int it = 1; it < COARSE_IT; ++it) {
      const int w = tid >> 6, l = tid & 63;
      const int xb = (w << 8) + (l << 2);
      float4 xv;
      xv.x = ldA(xc_cur + xb + 0); xv.y = ldA(xc_cur + xb + 1);
      xv.z = ldA(xc_cur + xb + 2); xv.w = ldA(xc_cur + xb + 3);
      float acc[16];
#pragma unroll
      for (int r2 = 0; r2 < 16; ++r2) {
        const __half2* hp2 = (const __half2*)(slab + (r2 << 12) + (w << 8) + (l << 2));
        const float2 f01 = __half22float2(hp2[0]);
        const float2 f23 = __half22float2(hp2[1]);
        acc[r2] = f01.x * xv.x + f01.y * xv.y + f23.x * xv.z + f23.y * xv.w;
      }
#pragma unroll
      for (int r2 = 0; r2 < 16; ++r2) {
        float v = acc[r2];
        v += __shfl_down(v, 32); v += __shfl_down(v, 16); v += __shfl_down(v, 8);
        v += __shfl_down(v, 4);  v += __shfl_down(v, 2);  v += __shfl_down(v, 1);
        acc[r2] = v;
      }
      if (l == 0) {
#pragma unroll
        for (int r2 = 0; r2 < 16; ++r2) rowbuf[(w << 4) + r2] = acc[r2];
      }
      __syncthreads();
      if (tid < 16) {
        float y = 0.f;
#pragma unroll
        for (int w2 = 0; w2 < 16; ++w2) y += rowbuf[(w2 << 4) + tid];
        const float xo = ldA(xc_cur + (blk << 4) + tid);
        stA(&xc_nxt[(blk << 4) + tid], xo + (bcl[tid] - y) * wdiag[tid]);
      }
      float* tmp = (float*)xc_cur; xc_cur = xc_nxt; xc_nxt = tmp;
      gbar(bar, bs);
    }
    // ---- prolongation (in-place; xr is never x_in here since PRE_IT >= 1) ----
    {
      float* xw = (float*)xr;
      const float corr = pvg.x * ldA(xc_cur + pcg.x) + pvg.y * ldA(xc_cur + pcg.y) +
                         pvg.z * ldA(xc_cur + pcg.z) + pvg.w * ldA(xc_cur + pcg.w);
      stA(xw + g, ldA(xr + g) + corr);
      gbar(bar, bs);
    }
    // ---- post-smooth x3 ----
    for (int it = 0; it < POST_IT; ++it) {
      float s = 0.f;
#pragma unroll
      for (int j = 0; j < DD; ++j) s += av[j] * ldA(xr + ac[j]);
      const float xn = ldA(xr + g) + (bg - s) * wdg;
      float* wb = (wi == 0) ? x2 : out;
      stA(wb + g, xn);
      xr = wb; wi ^= 1;
      if (!(cyc == num - 1 && it == POST_IT - 1)) gbar(bar, bs);
    }
  }
}

extern "C" void kernel_launch(void* const* d_in, const int* in_sizes, int n_in,
                              void* d_out, int out_size, void* d_ws, size_t ws_size,
                              hipStream_t stream) {
  (void)in_sizes; (void)n_in; (void)out_size; (void)ws_size;
  const float* b      = (const float*)d_in[0];
  const float* x_in   = (const float*)d_in[1];
  const float* A_vals = (const float*)d_in[2];
  const float* P_vals = (const float*)d_in[3];
  const int*   A_cols = (const int*)d_in[4];
  const int*   P_cols = (const int*)d_in[5];
  const int*   num_p  = (const int*)d_in[6];
  float* out = (float*)d_out;

  char* ws = (char*)d_ws;
  unsigned* cnt    = (unsigned*)(ws + 0);                        // 16 KB (becomes cursor)
  unsigned* offs   = (unsigned*)(ws + 16384);                    // 4097 u32
  float*    xcA    = (float*)(ws + 36864);                       // 16 KB
  float*    xcB    = (float*)(ws + 53248);                       // 16 KB
  unsigned* bar    = (unsigned*)(ws + 69632);                    // 160 slots x 1152 B
  uint2*    pairs8 = (uint2*)(ws + 262144);                      // 8 MB
  uint4*    Ppack  = (uint4*)(ws + 262144 + 8388608);            // 4 MB
  unsigned* Y      = (unsigned*)(ws + 262144 + 8388608 + 4194304);// 20 MB (80B x N)
  // partials (4MB) and x2 (1MB) alias Y: Y is dead once the build phase (guarded
  // by gbar) completes, and each launch rebuilds Y from scratch.
  float* partials  = (float*)Y;
  float* x2        = (float*)((char*)Y + 4194304);

  hipMemsetAsync(cnt, 0, NCC * sizeof(unsigned), stream);
  hipMemsetAsync(bar, 0, 160 * BAR_SLOT_U32 * sizeof(unsigned), stream);
  hipLaunchKernelGGL(k_hist,    dim3(64),  dim3(1024), 0, stream,
                     (const int4*)P_cols, (const float4*)P_vals, cnt, Ppack);
  hipLaunchKernelGGL(k_scan,    dim3(1),   dim3(1024), 0, stream, cnt, offs);
  hipLaunchKernelGGL(k_scatter, dim3(64),  dim3(1024), 0, stream,
                     (const int4*)P_cols, (const float4*)P_vals, cnt, pairs8);
  hipLaunchKernelGGL(k_buildY,  dim3(256), dim3(1024), 0, stream,
                     A_vals, A_cols, (const uint4*)Ppack, Y);

  const unsigned smem_bytes = 131072 + 16384 + 64 + 64;          // 147584 B < 160 KB
  hipFuncSetAttribute((const void*)k_mega,
                      hipFuncAttributeMaxDynamicSharedMemorySize, (int)smem_bytes);
  void* args[] = { (void*)&b, (void*)&x_in, (void*)&A_vals, (void*)&P_vals,
                   (void*)&A_cols, (void*)&P_cols, (void*)&num_p,
                   (void*)&offs, (void*)&pairs8, (void*)&Y, (void*)&bar,
                   (void*)&partials, (void*)&x2,
                   (void*)&xcA, (void*)&xcB, (void*)&out };
  hipLaunchCooperativeKernel((void*)k_mega, dim3(256), dim3(1024), args, smem_bytes, stream);
}